// Round 6
// baseline (426.699 us; speedup 1.0000x reference)
//
#include <hip/hip_runtime.h>
#include <hip/hip_fp16.h>
#include <math.h>

// DSSIM (mean), B=32 C=3 H=W=512 fp32, separable 11x11 Gaussian.
// R5 = R4 (sliding ring + packed-FP32 math, 157 us) + fp16-packed LDS ring.
//  - Evidence: R2 (VALU 60%) and R4 (VALU 46%) both ~160 us -> not VALU-
//    bound; all pipes <50%; latency/barrier-bound at 12 waves/CU (52 KB LDS
//    = 3 blocks/CU). Fix: shrink LDS so 5 blocks fit.
//  - Ring planes in fp16: per px uint2{half2(mu1,mu2), half2(e11,e22)} in
//    sAB (80 B/slot, b64 reads, 2-way banks = free) + half e12 in sC
//    (16 B/slot). LDS 52.1 -> 27.8 KB => 5 blocks/CU (20 waves).
//  - fp16 RTN on [0,1] values: ulp ~5e-4 rel, unbiased; mean-level error
//    ~1e-4 << 9.9e-3 threshold.
//  - NO lambdas/helpers with array args (R3: scratch demotion disaster);
//    packing via macro.

namespace {
constexpr int IMG = 512;
constexpr int TW = 32;                 // strip width
constexpr int RB = 64;                 // output rows per chunk
constexpr int RING = RB + 10;          // 74 ring rows
constexpr int SLOT_AB = 10;            // uint2 per (xg,row) slot: 8 px + 2 pad
constexpr int SLOT_C  = 8;             // ushort per (xg,row) slot: 8 px
constexpr int XGN = TW / 8;            // 4 col-groups
constexpr int NCHUNK = IMG / RB;       // 8
constexpr int CTILES = IMG / TW;       // 16 strips per image
constexpr int NIMG = 96;               // 32*3
constexpr float C1c = 1e-4f;
constexpr float C2c = 9e-4f;
constexpr float INV_N = 1.0f / 25165824.0f;  // 1/(96*512*512)
}

typedef float v2f __attribute__((ext_vector_type(2)));

#define PACK2(lo, hi) \
  ((unsigned)__half_as_ushort(__float2half_rn(lo)) | \
   ((unsigned)__half_as_ushort(__float2half_rn(hi)) << 16))

__global__ void dssim_zero(float* ws) { ws[0] = 0.0f; }

__global__ void dssim_final(const float* __restrict__ ws, float* __restrict__ out) {
  out[0] = ws[0] * INV_N;
}

__global__ __launch_bounds__(256, 5) void dssim_main(
    const float* __restrict__ im1, const float* __restrict__ im2,
    const float* __restrict__ gk, float* __restrict__ ws)
{
  __shared__ uint2          sAB[XGN * RING * SLOT_AB];  // 23,680 B
  __shared__ unsigned short sC [XGN * RING * SLOT_C];   //  4,736 B

  const int tid = threadIdx.x;
  const int bid = blockIdx.x;
  const int img = bid >> 4;
  const int tsx = bid & 15;
  const int X0s = tsx * TW;

  const float* __restrict__ p1 = im1 + (size_t)img * (IMG * IMG);
  const float* __restrict__ p2 = im2 + (size_t)img * (IMG * IMG);

  // k1[i] = k2d[i][5] / sqrt(k2d[5][5])  (separable, sum(k1)=1)
  float wt[11];
  {
    float ic = 1.0f / sqrtf(gk[5 * 11 + 5]);
    #pragma unroll
    for (int i = 0; i < 11; ++i) wt[i] = gk[i * 11 + 5] * ic;
  }
  // packed weight pairs: wp[m] = {wte(m), wte(m-1)}, wte zero-padded
  v2f wp[12];
  #pragma unroll
  for (int m = 0; m < 12; ++m) {
    float lo = (m <= 10) ? wt[m] : 0.f;
    float hi = (m >= 1) ? wt[m - 1] : 0.f;
    wp[m].x = lo; wp[m].y = hi;
  }

  // v-phase mapping
  const int c   = tid & 31;
  const int yg  = tid >> 5;
  const int xg3 = c >> 3;
  const int cl  = c & 7;

  float lsum = 0.f;

  for (int k = 0; k < NCHUNK; ++k) {
    // ---- h-phase: produce new h-rows into the ring ----
    const int r0    = (k == 0) ? -5 : RB * k + 5;
    const int ntask = (k == 0) ? XGN * RING : XGN * RB;
    for (int t = tid; t < ntask; t += 256) {
      const int xg = t & 3, dr = t >> 2;
      const int r  = r0 + dr;
      const int rr = (r + 5) % RING;      // ring slot row
      const int cb = X0s + xg * 8 - 8;

      float a24[24], b24[24];
      if ((unsigned)r < (unsigned)IMG) {
        const float* row1 = p1 + r * IMG;
        const float* row2 = p2 + r * IMG;
        if (cb >= 0 && cb + 24 <= IMG) {
          #pragma unroll
          for (int i = 0; i < 6; ++i) {
            float4 v1 = *(const float4*)(row1 + cb + 4 * i);
            float4 v2 = *(const float4*)(row2 + cb + 4 * i);
            a24[4*i+0] = v1.x; a24[4*i+1] = v1.y; a24[4*i+2] = v1.z; a24[4*i+3] = v1.w;
            b24[4*i+0] = v2.x; b24[4*i+1] = v2.y; b24[4*i+2] = v2.z; b24[4*i+3] = v2.w;
          }
        } else {
          #pragma unroll
          for (int e = 0; e < 24; ++e) {
            int cc = cb + e;
            bool ok = (unsigned)cc < (unsigned)IMG;
            a24[e] = ok ? row1[cc] : 0.f;
            b24[e] = ok ? row2[cc] : 0.f;
          }
        }
      } else {
        #pragma unroll
        for (int e = 0; e < 24; ++e) { a24[e] = 0.f; b24[e] = 0.f; }
      }

      v2f o0[4], o1[4], o2[4], o3[4], o4[4];
      #pragma unroll
      for (int jp = 0; jp < 4; ++jp) {
        o0[jp] = 0.f; o1[jp] = 0.f; o2[jp] = 0.f; o3[jp] = 0.f; o4[jp] = 0.f;
      }
      #pragma unroll
      for (int e = 0; e < 18; ++e) {
        float va = a24[e + 3], vb = b24[e + 3];
        float pa = va * va, pb = vb * vb, pab = va * vb;
        v2f va2; va2.x = va; va2.y = va;
        v2f vb2; vb2.x = vb; vb2.y = vb;
        v2f pa2; pa2.x = pa; pa2.y = pa;
        v2f pb2; pb2.x = pb; pb2.y = pb;
        v2f pc2; pc2.x = pab; pc2.y = pab;
        #pragma unroll
        for (int jp = 0; jp < 4; ++jp) {
          int m = e - 2 * jp;
          if (m >= 0 && m < 12) {
            v2f w = wp[m];
            o0[jp] = __builtin_elementwise_fma(w, va2, o0[jp]);
            o1[jp] = __builtin_elementwise_fma(w, vb2, o1[jp]);
            o2[jp] = __builtin_elementwise_fma(w, pa2, o2[jp]);
            o3[jp] = __builtin_elementwise_fma(w, pb2, o3[jp]);
            o4[jp] = __builtin_elementwise_fma(w, pc2, o4[jp]);
          }
        }
      }

      // pack to fp16 and store: 4x b128 into sAB, 1x b128 into sC
      const int baseAB = (xg * RING + rr) * SLOT_AB;
      #pragma unroll
      for (int jp = 0; jp < 4; ++jp) {
        unsigned u0x = PACK2(o0[jp].x, o1[jp].x);
        unsigned u0y = PACK2(o2[jp].x, o3[jp].x);
        unsigned u1x = PACK2(o0[jp].y, o1[jp].y);
        unsigned u1y = PACK2(o2[jp].y, o3[jp].y);
        *(uint4*)&sAB[baseAB + 2 * jp] = make_uint4(u0x, u0y, u1x, u1y);
      }
      const int baseC = (xg * RING + rr) * SLOT_C;
      {
        unsigned w0 = PACK2(o4[0].x, o4[0].y);
        unsigned w1 = PACK2(o4[1].x, o4[1].y);
        unsigned w2 = PACK2(o4[2].x, o4[2].y);
        unsigned w3 = PACK2(o4[3].x, o4[3].y);
        *(uint4*)&sC[baseC] = make_uint4(w0, w1, w2, w3);
      }
    }
    __syncthreads();

    // ---- v-phase: 8 output rows per thread (4 packed pairs) + SSIM ----
    v2f m1p[4], m2p[4], e11p[4], e22p[4], e12p[4];
    #pragma unroll
    for (int jp = 0; jp < 4; ++jp) {
      m1p[jp] = 0.f; m2p[jp] = 0.f; e11p[jp] = 0.f; e22p[jp] = 0.f; e12p[jp] = 0.f;
    }

    const int rbase = (RB * k + yg * 8) % RING;
    #pragma unroll
    for (int rr = 0; rr < 18; ++rr) {
      int idx = rbase + rr;
      if (idx >= RING) idx -= RING;
      uint2 vab = sAB[(xg3 * RING + idx) * SLOT_AB + cl];
      unsigned short uc = sC[(xg3 * RING + idx) * SLOT_C + cl];
      __half2 hmu = *(const __half2*)&vab.x;
      __half2 hee = *(const __half2*)&vab.y;
      float f1 = __low2float(hmu), f2 = __high2float(hmu);
      float f3 = __low2float(hee), f4 = __high2float(hee);
      float f5 = __half2float(__ushort_as_half(uc));
      v2f x1; x1.x = f1; x1.y = f1;
      v2f x2; x2.x = f2; x2.y = f2;
      v2f x3; x3.x = f3; x3.y = f3;
      v2f x4; x4.x = f4; x4.y = f4;
      v2f x5; x5.x = f5; x5.y = f5;
      #pragma unroll
      for (int jp = 0; jp < 4; ++jp) {
        int m = rr - 2 * jp;
        if (m >= 0 && m < 12) {
          v2f w = wp[m];
          m1p[jp]  = __builtin_elementwise_fma(w, x1, m1p[jp]);
          m2p[jp]  = __builtin_elementwise_fma(w, x2, m2p[jp]);
          e11p[jp] = __builtin_elementwise_fma(w, x3, e11p[jp]);
          e22p[jp] = __builtin_elementwise_fma(w, x4, e22p[jp]);
          e12p[jp] = __builtin_elementwise_fma(w, x5, e12p[jp]);
        }
      }
    }

    #pragma unroll
    for (int jp = 0; jp < 4; ++jp) {
      v2f m1 = m1p[jp], m2 = m2p[jp];
      v2f m1s = m1 * m1, m2s = m2 * m2, m12 = m1 * m2;
      v2f s11 = e11p[jp] - m1s, s22 = e22p[jp] - m2s, s12 = e12p[jp] - m12;
      v2f num = (2.f * m12 + C1c) * (2.f * s12 + C2c);
      v2f den = (m1s + m2s + C1c) * (s11 + s22 + C2c);
      lsum += (1.f - num.x * __builtin_amdgcn_rcpf(den.x)) * 0.5f;
      lsum += (1.f - num.y * __builtin_amdgcn_rcpf(den.y)) * 0.5f;
    }
    __syncthreads();
  }

  // wave-level reduce, one atomic per wave
  #pragma unroll
  for (int off = 32; off > 0; off >>= 1) lsum += __shfl_down(lsum, off);
  if ((tid & 63) == 0) atomicAdd(ws, lsum);
}

extern "C" void kernel_launch(void* const* d_in, const int* in_sizes, int n_in,
                              void* d_out, int out_size, void* d_ws, size_t ws_size,
                              hipStream_t stream) {
  const float* im1 = (const float*)d_in[0];
  const float* im2 = (const float*)d_in[1];
  const float* gk  = (const float*)d_in[2];
  float* out = (float*)d_out;
  float* ws  = (float*)d_ws;

  hipLaunchKernelGGL(dssim_zero, dim3(1), dim3(1), 0, stream, ws);
  hipLaunchKernelGGL(dssim_main, dim3(NIMG * CTILES), dim3(256), 0, stream,
                     im1, im2, gk, ws);
  hipLaunchKernelGGL(dssim_final, dim3(1), dim3(1), 0, stream, ws, out);
}

// Round 7
// 295.559 us; speedup vs baseline: 1.4437x; 1.4437x over previous
//
#include <hip/hip_runtime.h>
#include <hip/hip_fp16.h>
#include <math.h>

// DSSIM (mean), B=32 C=3 H=W=512 fp32, separable 11x11 Gaussian.
// R6 = R5 (fp16-packed LDS ring) with __launch_bounds__(256,4) not (256,5).
//  - R5's (256,5) forced VGPR->48: scratch spill (WRITE_SIZE 192B -> 150MB,
//    FETCH 285 -> 612MB), 157 -> 300us. Cap 128 VGPR leaves headroom (~90
//    needed) while LDS 28.4KB still admits 5 blocks/CU = 20 waves.
//  - Clean A/B for the residency theory: R4 (52KB LDS, 12 waves/CU, 157us)
//    vs same math at 20 waves/CU.
//  - Ring planes fp16: uint2{half2(mu1,mu2), half2(e11,e22)} + half e12.
//  - NO lambdas/helpers with array args (R3 scratch lesson).

namespace {
constexpr int IMG = 512;
constexpr int TW = 32;                 // strip width
constexpr int RB = 64;                 // output rows per chunk
constexpr int RING = RB + 10;          // 74 ring rows
constexpr int SLOT_AB = 10;            // uint2 per (xg,row) slot: 8 px + 2 pad
constexpr int SLOT_C  = 8;             // ushort per (xg,row) slot: 8 px
constexpr int XGN = TW / 8;            // 4 col-groups
constexpr int NCHUNK = IMG / RB;       // 8
constexpr int CTILES = IMG / TW;       // 16 strips per image
constexpr int NIMG = 96;               // 32*3
constexpr float C1c = 1e-4f;
constexpr float C2c = 9e-4f;
constexpr float INV_N = 1.0f / 25165824.0f;  // 1/(96*512*512)
}

typedef float v2f __attribute__((ext_vector_type(2)));

#define PACK2(lo, hi) \
  ((unsigned)__half_as_ushort(__float2half_rn(lo)) | \
   ((unsigned)__half_as_ushort(__float2half_rn(hi)) << 16))

__global__ void dssim_zero(float* ws) { ws[0] = 0.0f; }

__global__ void dssim_final(const float* __restrict__ ws, float* __restrict__ out) {
  out[0] = ws[0] * INV_N;
}

__global__ __launch_bounds__(256, 4) void dssim_main(
    const float* __restrict__ im1, const float* __restrict__ im2,
    const float* __restrict__ gk, float* __restrict__ ws)
{
  __shared__ uint2          sAB[XGN * RING * SLOT_AB];  // 23,680 B
  __shared__ unsigned short sC [XGN * RING * SLOT_C];   //  4,736 B

  const int tid = threadIdx.x;
  const int bid = blockIdx.x;
  const int img = bid >> 4;
  const int tsx = bid & 15;
  const int X0s = tsx * TW;

  const float* __restrict__ p1 = im1 + (size_t)img * (IMG * IMG);
  const float* __restrict__ p2 = im2 + (size_t)img * (IMG * IMG);

  // k1[i] = k2d[i][5] / sqrt(k2d[5][5])  (separable, sum(k1)=1)
  float wt[11];
  {
    float ic = 1.0f / sqrtf(gk[5 * 11 + 5]);
    #pragma unroll
    for (int i = 0; i < 11; ++i) wt[i] = gk[i * 11 + 5] * ic;
  }
  // packed weight pairs: wp[m] = {wte(m), wte(m-1)}, wte zero-padded
  v2f wp[12];
  #pragma unroll
  for (int m = 0; m < 12; ++m) {
    float lo = (m <= 10) ? wt[m] : 0.f;
    float hi = (m >= 1) ? wt[m - 1] : 0.f;
    wp[m].x = lo; wp[m].y = hi;
  }

  // v-phase mapping
  const int c   = tid & 31;
  const int yg  = tid >> 5;
  const int xg3 = c >> 3;
  const int cl  = c & 7;

  float lsum = 0.f;

  for (int k = 0; k < NCHUNK; ++k) {
    // ---- h-phase: produce new h-rows into the ring ----
    const int r0    = (k == 0) ? -5 : RB * k + 5;
    const int ntask = (k == 0) ? XGN * RING : XGN * RB;
    for (int t = tid; t < ntask; t += 256) {
      const int xg = t & 3, dr = t >> 2;
      const int r  = r0 + dr;
      const int rr = (r + 5) % RING;      // ring slot row
      const int cb = X0s + xg * 8 - 8;

      float a24[24], b24[24];
      if ((unsigned)r < (unsigned)IMG) {
        const float* row1 = p1 + r * IMG;
        const float* row2 = p2 + r * IMG;
        if (cb >= 0 && cb + 24 <= IMG) {
          #pragma unroll
          for (int i = 0; i < 6; ++i) {
            float4 v1 = *(const float4*)(row1 + cb + 4 * i);
            float4 v2 = *(const float4*)(row2 + cb + 4 * i);
            a24[4*i+0] = v1.x; a24[4*i+1] = v1.y; a24[4*i+2] = v1.z; a24[4*i+3] = v1.w;
            b24[4*i+0] = v2.x; b24[4*i+1] = v2.y; b24[4*i+2] = v2.z; b24[4*i+3] = v2.w;
          }
        } else {
          #pragma unroll
          for (int e = 0; e < 24; ++e) {
            int cc = cb + e;
            bool ok = (unsigned)cc < (unsigned)IMG;
            a24[e] = ok ? row1[cc] : 0.f;
            b24[e] = ok ? row2[cc] : 0.f;
          }
        }
      } else {
        #pragma unroll
        for (int e = 0; e < 24; ++e) { a24[e] = 0.f; b24[e] = 0.f; }
      }

      v2f o0[4], o1[4], o2[4], o3[4], o4[4];
      #pragma unroll
      for (int jp = 0; jp < 4; ++jp) {
        o0[jp] = 0.f; o1[jp] = 0.f; o2[jp] = 0.f; o3[jp] = 0.f; o4[jp] = 0.f;
      }
      #pragma unroll
      for (int e = 0; e < 18; ++e) {
        float va = a24[e + 3], vb = b24[e + 3];
        float pa = va * va, pb = vb * vb, pab = va * vb;
        v2f va2; va2.x = va; va2.y = va;
        v2f vb2; vb2.x = vb; vb2.y = vb;
        v2f pa2; pa2.x = pa; pa2.y = pa;
        v2f pb2; pb2.x = pb; pb2.y = pb;
        v2f pc2; pc2.x = pab; pc2.y = pab;
        #pragma unroll
        for (int jp = 0; jp < 4; ++jp) {
          int m = e - 2 * jp;
          if (m >= 0 && m < 12) {
            v2f w = wp[m];
            o0[jp] = __builtin_elementwise_fma(w, va2, o0[jp]);
            o1[jp] = __builtin_elementwise_fma(w, vb2, o1[jp]);
            o2[jp] = __builtin_elementwise_fma(w, pa2, o2[jp]);
            o3[jp] = __builtin_elementwise_fma(w, pb2, o3[jp]);
            o4[jp] = __builtin_elementwise_fma(w, pc2, o4[jp]);
          }
        }
      }

      // pack to fp16 and store: 4x b128 into sAB, 1x b128 into sC
      const int baseAB = (xg * RING + rr) * SLOT_AB;
      #pragma unroll
      for (int jp = 0; jp < 4; ++jp) {
        unsigned u0x = PACK2(o0[jp].x, o1[jp].x);
        unsigned u0y = PACK2(o2[jp].x, o3[jp].x);
        unsigned u1x = PACK2(o0[jp].y, o1[jp].y);
        unsigned u1y = PACK2(o2[jp].y, o3[jp].y);
        *(uint4*)&sAB[baseAB + 2 * jp] = make_uint4(u0x, u0y, u1x, u1y);
      }
      const int baseC = (xg * RING + rr) * SLOT_C;
      {
        unsigned w0 = PACK2(o4[0].x, o4[0].y);
        unsigned w1 = PACK2(o4[1].x, o4[1].y);
        unsigned w2 = PACK2(o4[2].x, o4[2].y);
        unsigned w3 = PACK2(o4[3].x, o4[3].y);
        *(uint4*)&sC[baseC] = make_uint4(w0, w1, w2, w3);
      }
    }
    __syncthreads();

    // ---- v-phase: 8 output rows per thread (4 packed pairs) + SSIM ----
    v2f m1p[4], m2p[4], e11p[4], e22p[4], e12p[4];
    #pragma unroll
    for (int jp = 0; jp < 4; ++jp) {
      m1p[jp] = 0.f; m2p[jp] = 0.f; e11p[jp] = 0.f; e22p[jp] = 0.f; e12p[jp] = 0.f;
    }

    const int rbase = (RB * k + yg * 8) % RING;
    #pragma unroll
    for (int rr = 0; rr < 18; ++rr) {
      int idx = rbase + rr;
      if (idx >= RING) idx -= RING;
      uint2 vab = sAB[(xg3 * RING + idx) * SLOT_AB + cl];
      unsigned short uc = sC[(xg3 * RING + idx) * SLOT_C + cl];
      __half2 hmu = *(const __half2*)&vab.x;
      __half2 hee = *(const __half2*)&vab.y;
      float f1 = __low2float(hmu), f2 = __high2float(hmu);
      float f3 = __low2float(hee), f4 = __high2float(hee);
      float f5 = __half2float(__ushort_as_half(uc));
      v2f x1; x1.x = f1; x1.y = f1;
      v2f x2; x2.x = f2; x2.y = f2;
      v2f x3; x3.x = f3; x3.y = f3;
      v2f x4; x4.x = f4; x4.y = f4;
      v2f x5; x5.x = f5; x5.y = f5;
      #pragma unroll
      for (int jp = 0; jp < 4; ++jp) {
        int m = rr - 2 * jp;
        if (m >= 0 && m < 12) {
          v2f w = wp[m];
          m1p[jp]  = __builtin_elementwise_fma(w, x1, m1p[jp]);
          m2p[jp]  = __builtin_elementwise_fma(w, x2, m2p[jp]);
          e11p[jp] = __builtin_elementwise_fma(w, x3, e11p[jp]);
          e22p[jp] = __builtin_elementwise_fma(w, x4, e22p[jp]);
          e12p[jp] = __builtin_elementwise_fma(w, x5, e12p[jp]);
        }
      }
    }

    #pragma unroll
    for (int jp = 0; jp < 4; ++jp) {
      v2f m1 = m1p[jp], m2 = m2p[jp];
      v2f m1s = m1 * m1, m2s = m2 * m2, m12 = m1 * m2;
      v2f s11 = e11p[jp] - m1s, s22 = e22p[jp] - m2s, s12 = e12p[jp] - m12;
      v2f num = (2.f * m12 + C1c) * (2.f * s12 + C2c);
      v2f den = (m1s + m2s + C1c) * (s11 + s22 + C2c);
      lsum += (1.f - num.x * __builtin_amdgcn_rcpf(den.x)) * 0.5f;
      lsum += (1.f - num.y * __builtin_amdgcn_rcpf(den.y)) * 0.5f;
    }
    __syncthreads();
  }

  // wave-level reduce, one atomic per wave
  #pragma unroll
  for (int off = 32; off > 0; off >>= 1) lsum += __shfl_down(lsum, off);
  if ((tid & 63) == 0) atomicAdd(ws, lsum);
}

extern "C" void kernel_launch(void* const* d_in, const int* in_sizes, int n_in,
                              void* d_out, int out_size, void* d_ws, size_t ws_size,
                              hipStream_t stream) {
  const float* im1 = (const float*)d_in[0];
  const float* im2 = (const float*)d_in[1];
  const float* gk  = (const float*)d_in[2];
  float* out = (float*)d_out;
  float* ws  = (float*)d_ws;

  hipLaunchKernelGGL(dssim_zero, dim3(1), dim3(1), 0, stream, ws);
  hipLaunchKernelGGL(dssim_main, dim3(NIMG * CTILES), dim3(256), 0, stream,
                     im1, im2, gk, ws);
  hipLaunchKernelGGL(dssim_final, dim3(1), dim3(1), 0, stream, ws, out);
}